// Round 1
// baseline (307.782 us; speedup 1.0000x reference)
//
#include <hip/hip_runtime.h>
#include <hip/hip_bf16.h>

// Problem: y[b,o,h,w] = sum_c mean_i(W[i,o,c]) * x[b,c,h,w] + mean_i(B[i,o])
// B=16, Cin=Cout=64, H=W=256. All fp32.
// x layout:  [16][64][65536]   (256 MiB)
// out layout:[16][64][65536]   (256 MiB)

#define HW 65536          // 256*256
#define CIN 64
#define COUT 64
#define NB 16
#define NCONV 9

// ---- pre-kernel: reduce weights/biases to their means in d_ws ----
// ws layout: [0..4095]  = Wm[o][c]  (o*64+c)
//            [4096..4159] = Bm[o]
__global__ void reduce_wb_kernel(const float* __restrict__ w,
                                 const float* __restrict__ b,
                                 float* __restrict__ ws) {
    int tid = blockIdx.x * blockDim.x + threadIdx.x;
    const float inv9 = 1.0f / 9.0f;
    if (tid < COUT * CIN) {
        float s = 0.f;
        #pragma unroll
        for (int i = 0; i < NCONV; ++i) s += w[i * (COUT * CIN) + tid];
        ws[tid] = s * inv9;
    } else if (tid < COUT * CIN + COUT) {
        int o = tid - COUT * CIN;
        float s = 0.f;
        #pragma unroll
        for (int i = 0; i < NCONV; ++i) s += b[i * COUT + o];
        ws[COUT * CIN + o] = s * inv9;
    }
}

// ---- main kernel: one thread per spatial position ----
__global__ __launch_bounds__(256) void conv1x1_kernel(
        const float* __restrict__ x,
        const float* __restrict__ ws,
        float* __restrict__ out) {
    // global position index p = b*HW + hw, p in [0, 16*65536)
    unsigned p = blockIdx.x * blockDim.x + threadIdx.x;
    unsigned b = p >> 16;
    unsigned hw = p & (HW - 1);
    // base element offset of (b, c=0, hw); all offsets fit in 32 bits (max 2^26)
    unsigned xbase = b * (CIN * HW) + hw;

    const float* __restrict__ wm = ws;              // [64][64]
    const float* __restrict__ bm = ws + COUT * CIN; // [64]

    // load the 64 input channels for this position (coalesced across lanes)
    float xv[CIN];
    #pragma unroll
    for (int c = 0; c < CIN; ++c) {
        xv[c] = x[xbase + (unsigned)c * HW];
    }

    unsigned obase = b * (COUT * HW) + hw;
    // weights are wave-uniform -> compiler keeps them in SGPRs (s_load),
    // each FMA is v_fmac_f32 vdst, sgpr, vgpr.
    #pragma unroll 2
    for (int o = 0; o < COUT; ++o) {
        float acc = bm[o];
        #pragma unroll
        for (int c = 0; c < CIN; ++c) {
            acc = fmaf(wm[o * CIN + c], xv[c], acc);
        }
        out[obase + (unsigned)o * HW] = acc;
    }
}

extern "C" void kernel_launch(void* const* d_in, const int* in_sizes, int n_in,
                              void* d_out, int out_size, void* d_ws, size_t ws_size,
                              hipStream_t stream) {
    const float* x = (const float*)d_in[0];   // [16][64][256][256]
    const float* w = (const float*)d_in[1];   // [9][64][64][1][1]
    const float* b = (const float*)d_in[2];   // [9][64]
    float* out = (float*)d_out;
    float* ws = (float*)d_ws;                 // needs (4096+64)*4 = 16.6 KB

    // 1) reduce weights/biases
    int red_items = COUT * CIN + COUT;        // 4160
    int red_blocks = (red_items + 255) / 256; // 17
    reduce_wb_kernel<<<red_blocks, 256, 0, stream>>>(w, b, ws);

    // 2) main conv
    unsigned total = NB * HW;                 // 1,048,576 positions
    conv1x1_kernel<<<total / 256, 256, 0, stream>>>(x, ws, out);
}

// Round 2
// 152.962 us; speedup vs baseline: 2.0121x; 2.0121x over previous
//
#include <hip/hip_runtime.h>
#include <hip/hip_bf16.h>

// Y[b,o,hw] = sum_c mean_i(W[i,o,c]) * x[b,c,hw] + mean_i(B[i,o])
// B=16, Cin=Cout=64, H*W=65536, fp32 in/out.
// Strategy: fold 9 convs into one (linearity), then treat as GEMM
// Y[64 x 1M] = Wm[64x64] * X[64 x 1M] using bf16 MFMA 16x16x32.
// Each wave: W-fragments resident in VGPRs (loaded once), streams x once,
// no LDS, bias folded into accumulator init.

#define HW 65536
#define CIN 64
#define COUT 64
#define NB 16
#define NCONV 9

typedef short s16x8 __attribute__((ext_vector_type(8)));
typedef float f32x4 __attribute__((ext_vector_type(4)));

// float -> bf16 (RNE) as raw ushort bits
static __device__ __forceinline__ unsigned short f2bf(float f) {
    unsigned u = __builtin_bit_cast(unsigned, f);
    u = (u + 0x7FFFu + ((u >> 16) & 1u)) >> 16;
    return (unsigned short)u;
}

// ---- pre-kernel: ws[0..4095] = Wm[o][c] as bf16 (8KB); ws+8192: Bm[64] fp32 ----
__global__ void reduce_wb_kernel(const float* __restrict__ w,
                                 const float* __restrict__ b,
                                 void* __restrict__ wsv) {
    unsigned short* wm = (unsigned short*)wsv;
    float* bm = (float*)((char*)wsv + 8192);
    int tid = blockIdx.x * blockDim.x + threadIdx.x;
    const float inv9 = 1.0f / 9.0f;
    if (tid < COUT * CIN) {
        float s = 0.f;
        #pragma unroll
        for (int i = 0; i < NCONV; ++i) s += w[i * (COUT * CIN) + tid];
        wm[tid] = f2bf(s * inv9);
    } else if (tid < COUT * CIN + COUT) {
        int o = tid - COUT * CIN;
        float s = 0.f;
        #pragma unroll
        for (int i = 0; i < NCONV; ++i) s += b[i * COUT + o];
        bm[o] = s * inv9;
    }
}

// ---- main kernel: MFMA 16x16x32 bf16, one wave = 64 positions x all 64 outputs ----
__global__ __launch_bounds__(256) void conv1x1_mfma_kernel(
        const float* __restrict__ x,
        const void* __restrict__ wsv,
        float* __restrict__ out) {
    const unsigned short* wm = (const unsigned short*)wsv;     // bf16 bits [64][64]
    const float* bm = (const float*)((const char*)wsv + 8192); // fp32 [64]

    int tid  = threadIdx.x;
    int lane = tid & 63;
    int wave = tid >> 6;      // 0..3
    int l16  = lane & 15;
    int lg   = lane >> 4;     // 0..3

    // A fragments: afrag[m][ks] holds W[o = m*16 + l16][c = ks*32 + lg*8 + j], j=0..7
    s16x8 afrag[4][2];
    #pragma unroll
    for (int m = 0; m < 4; ++m) {
        #pragma unroll
        for (int ks = 0; ks < 2; ++ks) {
            int o = m * 16 + l16;
            int c = ks * 32 + lg * 8;
            afrag[m][ks] = *reinterpret_cast<const s16x8*>(wm + o * CIN + c);
        }
    }

    // bias per accumulator slot: D row = m*16 + lg*4 + r
    f32x4 binit[4];
    #pragma unroll
    for (int m = 0; m < 4; ++m) {
        #pragma unroll
        for (int r = 0; r < 4; ++r) {
            binit[m][r] = bm[m * 16 + lg * 4 + r];
        }
    }

    unsigned pbase  = blockIdx.x * 256u;          // global position b*HW+hw
    unsigned b      = pbase >> 16;                // HW = 2^16
    unsigned hwbase = (pbase & 65535u) + (unsigned)wave * 64u;
    const float* __restrict__ xb = x   + (size_t)b * CIN  * HW;
    float* __restrict__       ob = out + (size_t)b * COUT * HW;

    #pragma unroll
    for (int t = 0; t < 4; ++t) {                 // 4 n-tiles of 16 positions
        unsigned p = hwbase + (unsigned)t * 16u + (unsigned)l16;

        // B fragment loads: lane needs X[c = ks*32 + lg*8 + j][p], j=0..7
        float xf[16];
        #pragma unroll
        for (int ks = 0; ks < 2; ++ks) {
            unsigned c0 = (unsigned)(ks * 32 + lg * 8);
            #pragma unroll
            for (int j = 0; j < 8; ++j) {
                xf[ks * 8 + j] = xb[(c0 + (unsigned)j) * (unsigned)HW + p];
            }
        }
        s16x8 bfrag[2];
        #pragma unroll
        for (int ks = 0; ks < 2; ++ks) {
            #pragma unroll
            for (int j = 0; j < 8; ++j) {
                bfrag[ks][j] = (short)f2bf(xf[ks * 8 + j]);
            }
        }

        f32x4 acc[4];
        #pragma unroll
        for (int m = 0; m < 4; ++m) acc[m] = binit[m];

        #pragma unroll
        for (int ks = 0; ks < 2; ++ks) {
            #pragma unroll
            for (int m = 0; m < 4; ++m) {
                acc[m] = __builtin_amdgcn_mfma_f32_16x16x32_bf16(
                    afrag[m][ks], bfrag[ks], acc[m], 0, 0, 0);
            }
        }

        // D layout: col = lane&15 (position), row = lg*4 + r (output within m-tile)
        #pragma unroll
        for (int m = 0; m < 4; ++m) {
            #pragma unroll
            for (int r = 0; r < 4; ++r) {
                unsigned o = (unsigned)(m * 16 + lg * 4 + r);
                ob[o * (unsigned)HW + hwbase + (unsigned)t * 16u + (unsigned)l16] = acc[m][r];
            }
        }
    }
}

extern "C" void kernel_launch(void* const* d_in, const int* in_sizes, int n_in,
                              void* d_out, int out_size, void* d_ws, size_t ws_size,
                              hipStream_t stream) {
    const float* x = (const float*)d_in[0];   // [16][64][256][256]
    const float* w = (const float*)d_in[1];   // [9][64][64][1][1]
    const float* b = (const float*)d_in[2];   // [9][64]
    float* out = (float*)d_out;

    // 1) reduce weights/biases -> ws (bf16 Wm + fp32 Bm)
    int red_items  = COUT * CIN + COUT;        // 4160
    int red_blocks = (red_items + 255) / 256;  // 17
    reduce_wb_kernel<<<red_blocks, 256, 0, stream>>>(w, b, d_ws);

    // 2) main MFMA conv: 1,048,576 positions / 256 per block
    unsigned total = NB * HW;
    conv1x1_mfma_kernel<<<total / 256, 256, 0, stream>>>(x, d_ws, out);
}

// Round 3
// 115.058 us; speedup vs baseline: 2.6750x; 1.3294x over previous
//
#include <hip/hip_runtime.h>
#include <hip/hip_bf16.h>

// Y[b,o,hw] = mean_i(W[i,o,:]) . x[b,:,hw] + mean_i(B[i,o])
// B=16, Cin=Cout=64, HW=65536, fp32 in/out.
// GEMM via bf16 MFMA 16x16x32; x staged fp32 in LDS via global_load_lds
// (1KB per instr), output transposed through LDS for 512B-contiguous stores.

#define HW 65536
#define CIN 64
#define COUT 64
#define NB 16
#define NCONV 9
#define TP 128   // positions per block

typedef short s16x8 __attribute__((ext_vector_type(8)));
typedef float f32x4 __attribute__((ext_vector_type(4)));

// float -> bf16 (RNE) raw bits
static __device__ __forceinline__ unsigned short f2bf(float f) {
    unsigned u = __builtin_bit_cast(unsigned, f);
    u = (u + 0x7FFFu + ((u >> 16) & 1u)) >> 16;
    return (unsigned short)u;
}

// ---- pre-kernel: ws[0..8191]B = Wm[o][c] bf16; ws+8192: Bm[64] fp32 ----
__global__ void reduce_wb_kernel(const float* __restrict__ w,
                                 const float* __restrict__ b,
                                 void* __restrict__ wsv) {
    unsigned short* wm = (unsigned short*)wsv;
    float* bm = (float*)((char*)wsv + 8192);
    int tid = blockIdx.x * blockDim.x + threadIdx.x;
    const float inv9 = 1.0f / 9.0f;
    if (tid < COUT * CIN) {
        float s = 0.f;
        #pragma unroll
        for (int i = 0; i < NCONV; ++i) s += w[i * (COUT * CIN) + tid];
        wm[tid] = f2bf(s * inv9);
    } else if (tid < COUT * CIN + COUT) {
        int o = tid - COUT * CIN;
        float s = 0.f;
        #pragma unroll
        for (int i = 0; i < NCONV; ++i) s += b[i * COUT + o];
        bm[o] = s * inv9;
    }
}

// ---- main kernel ----
__global__ __launch_bounds__(256, 4) void conv1x1_mfma_lds_kernel(
        const float* __restrict__ x,
        const void* __restrict__ wsv,
        float* __restrict__ out) {
    __shared__ float lds[CIN * TP];   // 32 KB; x tile, then reused for out tile

    const unsigned short* wm = (const unsigned short*)wsv;     // bf16 [64][64]
    const float* bm = (const float*)((const char*)wsv + 8192); // fp32 [64]

    int tid  = threadIdx.x;
    int lane = tid & 63;
    int wave = tid >> 6;      // 0..3
    int l16  = lane & 15;
    int lg   = lane >> 4;     // 0..3

    unsigned pbase = blockIdx.x * (unsigned)TP;   // global position b*HW + hw
    unsigned b     = pbase >> 16;                 // HW = 2^16, TP divides HW
    unsigned p0    = pbase & 65535u;
    const float* __restrict__ xb = x   + (size_t)b * CIN  * HW + p0;
    float* __restrict__       ob = out + (size_t)b * COUT * HW + p0;

    // ---- async stage: 32 x global_load_lds(16B), each = 2 channel rows (1KB) ----
    {
        unsigned chalf = (unsigned)(lane >> 5);          // 0/1: which row of pair
        unsigned po    = (unsigned)(lane & 31) * 4u;     // float offset in row
        #pragma unroll
        for (int i = 0; i < 8; ++i) {
            int k = wave * 8 + i;                        // pair index 0..31
            const float* src = xb + ((unsigned)(2 * k) + chalf) * (unsigned)HW + po;
            __builtin_amdgcn_global_load_lds(
                (const __attribute__((address_space(1))) unsigned int*)src,
                (__attribute__((address_space(3))) unsigned int*)&lds[k * 256],
                16, 0, 0);
        }
    }

    // ---- W fragments + bias while loads are in flight ----
    // A frag: afrag[m][ks][j] = W[o = m*16 + l16][c = ks*32 + lg*8 + j]
    s16x8 afrag[4][2];
    #pragma unroll
    for (int m = 0; m < 4; ++m) {
        #pragma unroll
        for (int ks = 0; ks < 2; ++ks) {
            afrag[m][ks] = *reinterpret_cast<const s16x8*>(
                wm + (m * 16 + l16) * CIN + ks * 32 + lg * 8);
        }
    }
    f32x4 binit[4];
    #pragma unroll
    for (int m = 0; m < 4; ++m) {
        #pragma unroll
        for (int r = 0; r < 4; ++r) binit[m][r] = bm[m * 16 + lg * 4 + r];
    }

    __syncthreads();   // x tile resident

    // ---- compute: wave owns local positions wave*32 .. wave*32+31 (2 n-tiles) ----
    f32x4 acc[2][4];
    #pragma unroll
    for (int t = 0; t < 2; ++t) {
        int pl = wave * 32 + t * 16 + l16;           // local position
        float xf[16];
        #pragma unroll
        for (int ks = 0; ks < 2; ++ks) {
            #pragma unroll
            for (int j = 0; j < 8; ++j) {
                xf[ks * 8 + j] = lds[(ks * 32 + lg * 8 + j) * TP + pl];
            }
        }
        s16x8 bfrag[2];
        #pragma unroll
        for (int ks = 0; ks < 2; ++ks) {
            #pragma unroll
            for (int j = 0; j < 8; ++j) bfrag[ks][j] = (short)f2bf(xf[ks * 8 + j]);
        }
        #pragma unroll
        for (int m = 0; m < 4; ++m) acc[t][m] = binit[m];
        #pragma unroll
        for (int ks = 0; ks < 2; ++ks) {
            #pragma unroll
            for (int m = 0; m < 4; ++m) {
                acc[t][m] = __builtin_amdgcn_mfma_f32_16x16x32_bf16(
                    afrag[m][ks], bfrag[ks], acc[t][m], 0, 0, 0);
            }
        }
    }

    __syncthreads();   // all x reads done; safe to overwrite LDS

    // ---- acc -> LDS as [COUT][TP] ----
    // D layout: col = l16 (position), row = lg*4 + r within m-tile of 16
    #pragma unroll
    for (int t = 0; t < 2; ++t) {
        #pragma unroll
        for (int m = 0; m < 4; ++m) {
            #pragma unroll
            for (int r = 0; r < 4; ++r) {
                lds[(m * 16 + lg * 4 + r) * TP + wave * 32 + t * 16 + l16] =
                    acc[t][m][r];
            }
        }
    }

    __syncthreads();

    // ---- coalesced store: 8 iters, each thread one float4 ----
    int pq = tid & 31;          // float4 index in row (32 per row)
    int oo = tid >> 5;          // 0..7
    #pragma unroll
    for (int i = 0; i < 8; ++i) {
        int o = i * 8 + oo;
        f32x4 v = *reinterpret_cast<const f32x4*>(&lds[o * TP + pq * 4]);
        *reinterpret_cast<f32x4*>(ob + (unsigned)o * (unsigned)HW + (unsigned)(pq * 4)) = v;
    }
}

extern "C" void kernel_launch(void* const* d_in, const int* in_sizes, int n_in,
                              void* d_out, int out_size, void* d_ws, size_t ws_size,
                              hipStream_t stream) {
    const float* x = (const float*)d_in[0];   // [16][64][256][256]
    const float* w = (const float*)d_in[1];   // [9][64][64][1][1]
    const float* b = (const float*)d_in[2];   // [9][64]
    float* out = (float*)d_out;

    int red_items  = COUT * CIN + COUT;        // 4160
    int red_blocks = (red_items + 255) / 256;  // 17
    reduce_wb_kernel<<<red_blocks, 256, 0, stream>>>(w, b, d_ws);

    unsigned total_blocks = (NB * HW) / TP;    // 8192
    conv1x1_mfma_lds_kernel<<<total_blocks, 256, 0, stream>>>(x, d_ws, out);
}